// Round 1
// baseline (135.638 us; speedup 1.0000x reference)
//
#include <hip/hip_runtime.h>

// KLD RepPoints loss, R6: coalesced global->LDS staging.
// History: R0/R1 60us floor = same-line atomics. R2 two-kernel ~32us kernel.
// R3 (LDS dense staging, block-wide) and R4 (float4 pair gather) regressed.
// R5 (4 elems/thread, 52 outstanding loads) = NO change vs R2 -> NOT
// latency-bound. Diagnosis: 72B-stride float2 gather makes every wave-load
// touch ~64 cache lines -> ~832 L1 transactions per 64 elems (vs ~104
// coalesced) -> L1 request-throughput bound at ~22us/CU, 2x the 17.3us HBM
// roofline. R6: per-wave 64-elem chunks staged linearly into LDS with
// __builtin_amdgcn_global_load_lds (4 lines/instr), double-buffered,
// counted vmcnt(26) so the next-chunk prefetch stays in flight (T4),
// no block barriers. LDS read conflicts (pred 4-way b64, target 16-way
// b128) are sub-critical vs the HBM floor.

#define WAVES_PER_BLOCK 4

__device__ __forceinline__ float kld_elem(
    const float px[9], const float py[9],
    const float tx[4], const float ty[4])
{
    // ---- pred moments ----
    const float inv9 = 1.0f / 9.0f;
    float sx = 0.f, sy = 0.f;
    #pragma unroll
    for (int k = 0; k < 9; ++k) { sx += px[k]; sy += py[k]; }
    float mux = sx * inv9, muy = sy * inv9;
    float a = 0.f, b = 0.f, d = 0.f;   // p_var = [[a,b],[b,d]]
    #pragma unroll
    for (int k = 0; k < 9; ++k) {
        float xx = px[k] - mux, yy = py[k] - muy;
        a += xx * xx; b += xx * yy; d += yy * yy;
    }
    a = a * inv9 + 1e-6f;
    b = b * inv9;
    d = d * inv9 + 1e-6f;

    // ---- target box -> rotated Gaussian ----
    float tmux = (tx[0] + tx[1] + tx[2] + tx[3]) * 0.25f;
    float tmuy = (ty[0] + ty[1] + ty[2] + ty[3]) * 0.25f;
    float e1x = tx[1] - tx[0], e1y = ty[1] - ty[0];
    float e2x = tx[2] - tx[1], e2y = ty[2] - ty[1];
    float w = e1x * e1x + e1y * e1y;
    float h = e2x * e2x + e2y * e2y;
    float sw = sqrtf(w);
    float c = e1x / sw, s = e1y / sw;
    const float invLL = 1.0f / 36.0f;      // 1/(4*L*L), L=3
    float dw = w * invLL, dh = h * invLL;
    float tv00 = c * c * dw + s * s * dh;  // t_var = R diag(dw,dh) R^T
    float tv01 = c * s * (dw - dh);
    float tv11 = s * s * dw + c * c * dh;

    float t_det = tv00 * tv11 - tv01 * tv01;
    float p_det = a * d - b * b;
    float inv_tdet = 1.0f / t_det;

    float dx = mux - tmux, dy = muy - tmuy;
    float term1 = (dx * dx * tv11 - 2.0f * dx * dy * tv01 + dy * dy * tv00) * inv_tdet;
    float trace = (tv11 * a - 2.0f * tv01 * b + tv00 * d) * inv_tdet;
    float term2 = trace + logf(t_det / p_det);
    float kld = 0.5f * (term1 + term2) - 1.0f;
    float kl = fmaxf(kld, 1e-6f);
    return 1.0f - 1.0f / (2.0f + sqrtf(kl));
}

// direct (uncoalesced) path, used only for the n%64 tail
__device__ __forceinline__ float kld_direct(
    const float* __restrict__ pred, const float* __restrict__ target, size_t e)
{
    const float2* p = reinterpret_cast<const float2*>(pred) + e * 9;
    const float2* t = reinterpret_cast<const float2*>(target) + e * 4;
    float2 p0 = p[0], p1 = p[1], p2 = p[2], p3 = p[3], p4 = p[4],
           p5 = p[5], p6 = p[6], p7 = p[7], p8 = p[8];
    float2 q0 = t[0], q1 = t[1], q2 = t[2], q3 = t[3];
    float px[9] = {p0.x, p1.x, p2.x, p3.x, p4.x, p5.x, p6.x, p7.x, p8.x};
    float py[9] = {p0.y, p1.y, p2.y, p3.y, p4.y, p5.y, p6.y, p7.y, p8.y};
    float tx[4] = {q0.x, q1.x, q2.x, q3.x};
    float ty[4] = {q0.y, q1.y, q2.y, q3.y};
    return kld_elem(px, py, tx, ty);
}

// async global->LDS, 4B per lane. LDS dest = wave-uniform base + lane*4
// (linear), global src is per-lane.
__device__ __forceinline__ void gload_lds4(const float* g, float* l)
{
    __builtin_amdgcn_global_load_lds(
        (const __attribute__((address_space(1))) void*)g,
        (__attribute__((address_space(3))) void*)l,
        4, 0, 0);
}

// 64-element chunk: pred 1152 floats then target 512 floats, both linear.
// 26 global_load_lds instructions, each touching exactly 4 cache lines.
__device__ __forceinline__ void stage_chunk(
    const float* __restrict__ pred, const float* __restrict__ target,
    float* ldsreg, size_t chunk, int lane)
{
    const float* pg = pred   + chunk * 1152 + lane;
    const float* tg = target + chunk * 512  + lane;
    #pragma unroll
    for (int k = 0; k < 18; ++k)
        gload_lds4(pg + k * 64, ldsreg + k * 64);
    #pragma unroll
    for (int k = 0; k < 8; ++k)
        gload_lds4(tg + k * 64, ldsreg + 1152 + k * 64);
}

__global__ __launch_bounds__(256) void kld_partial_kernel(
    const float* __restrict__ pred,    // [n][9][2]
    const float* __restrict__ target,  // [n][4][2]
    float* __restrict__ ws,            // [gridDim.x] partial sums
    int n_total)
{
    // [wave][double-buffer][1152 pred + 512 target floats] = 53,248 B
    // -> 3 blocks/CU, 12 waves/CU; each wave keeps 6.6 KB in flight.
    __shared__ __align__(16) float lds[WAVES_PER_BLOCK][2][1664];

    const int lane        = threadIdx.x & 63;
    const int wid         = threadIdx.x >> 6;
    const int wave_gid    = blockIdx.x * WAVES_PER_BLOCK + wid;
    const int total_waves = gridDim.x * WAVES_PER_BLOCK;
    const int full_chunks = n_total >> 6;

    float loss = 0.0f;

    // tail (n % 64): one wave, direct path, fully drained before staging starts
    const int tail = n_total & 63;
    if (wave_gid == 0 && lane < tail)
        loss += kld_direct(pred, target, (size_t)full_chunks * 64 + lane);

    float* lds0 = &lds[wid][0][0];
    float* lds1 = &lds[wid][1][0];

    int c = wave_gid;
    if (c < full_chunks)
        stage_chunk(pred, target, lds0, (size_t)c, lane);

    int cur = 0;
    for (; c < full_chunks; c += total_waves) {
        float* ldscur = cur ? lds1 : lds0;
        float* ldsnxt = cur ? lds0 : lds1;

        // previous iteration's ds_reads have landed -> safe to overwrite ldsnxt
        asm volatile("s_waitcnt lgkmcnt(0)" ::: "memory");

        const int nxt = c + total_waves;
        if (nxt < full_chunks) {
            stage_chunk(pred, target, ldsnxt, (size_t)nxt, lane);
            // 26 newest outstanding = next chunk; everything older (= current
            // chunk's stage) has retired. Never drain to 0 mid-loop.
            asm volatile("s_waitcnt vmcnt(26)" ::: "memory");
        } else {
            asm volatile("s_waitcnt vmcnt(0)" ::: "memory");
        }

        // LDS -> regs: 9x ds_read_b64 (72B elem stride: 4-way, benign)
        const float2* pe = reinterpret_cast<const float2*>(ldscur) + lane * 9;
        float2 p0 = pe[0], p1 = pe[1], p2 = pe[2], p3 = pe[3], p4 = pe[4],
               p5 = pe[5], p6 = pe[6], p7 = pe[7], p8 = pe[8];
        // 2x ds_read_b128 (32B elem stride: 16-way, ~3us/CU total, hidden)
        const float4* te = reinterpret_cast<const float4*>(ldscur + 1152) + lane * 2;
        float4 t01 = te[0], t23 = te[1];

        float px[9] = {p0.x, p1.x, p2.x, p3.x, p4.x, p5.x, p6.x, p7.x, p8.x};
        float py[9] = {p0.y, p1.y, p2.y, p3.y, p4.y, p5.y, p6.y, p7.y, p8.y};
        float tx[4] = {t01.x, t01.z, t23.x, t23.z};
        float ty[4] = {t01.y, t01.w, t23.y, t23.w};
        loss += kld_elem(px, py, tx, ty);

        cur ^= 1;
    }

    // ---- reduction: wave64 shuffle -> LDS -> one plain store per block ----
    #pragma unroll
    for (int off = 32; off > 0; off >>= 1)
        loss += __shfl_down(loss, off, 64);

    __shared__ float sm[WAVES_PER_BLOCK];
    if (lane == 0) sm[wid] = loss;
    __syncthreads();
    if (threadIdx.x == 0)
        ws[blockIdx.x] = sm[0] + sm[1] + sm[2] + sm[3];
}

__global__ __launch_bounds__(256) void kld_final_kernel(
    const float* __restrict__ ws, float* __restrict__ out,
    int nblocks, float inv_n)
{
    float s = 0.0f;
    for (int i = threadIdx.x; i < nblocks; i += 256)
        s += ws[i];

    #pragma unroll
    for (int off = 32; off > 0; off >>= 1)
        s += __shfl_down(s, off, 64);

    __shared__ float sm[4];
    int lane = threadIdx.x & 63;
    int wid  = threadIdx.x >> 6;
    if (lane == 0) sm[wid] = s;
    __syncthreads();
    if (threadIdx.x == 0)
        out[0] = (sm[0] + sm[1] + sm[2] + sm[3]) * inv_n;
}

extern "C" void kernel_launch(void* const* d_in, const int* in_sizes, int n_in,
                              void* d_out, int out_size, void* d_ws, size_t ws_size,
                              hipStream_t stream) {
    const float* pred   = (const float*)d_in[0];
    const float* target = (const float*)d_in[1];
    float* out = (float*)d_out;
    float* ws  = (float*)d_ws;

    int n = in_sizes[0] / 18;   // N elements (pred is N*9*2 floats)
    int nblocks = (n + 256 * 4 - 1) / (256 * 4);
    if (nblocks < 1) nblocks = 1;

    kld_partial_kernel<<<nblocks, 256, 0, stream>>>(pred, target, ws, n);
    kld_final_kernel<<<1, 256, 0, stream>>>(ws, out, nblocks, 1.0f / (float)n);
}